// Round 2
// baseline (437.706 us; speedup 1.0000x reference)
//
#include <hip/hip_runtime.h>
#include <hip/hip_bf16.h>

#define EPSBN 1e-5f

// ---- workspace layout (bytes) ----
#define WS_WR    0         // 128 floats
#define WS_G     2048      // 512 floats  (g[b][c])
#define WS_CH    4096      // 512 floats  (ch_att)
#define WS_SP    6144      // 72  floats  (sp_att)
#define WS_KA    6656      // 16  floats  (k_att)
#define WS_S     7168      // 256 floats  (scale[b][o])
#define WS_T     8192      // 32  floats  (bias[o])
#define WS_AGG   16384     // 147456 floats, layout [b][ci][9][o(32)]

// ---------------- K0: per-input-row total bilinear weights Wr[128] ----------------
__global__ void k_wr(float* __restrict__ wr){
  int i = threadIdx.x;            // 0..127
  float s = 0.f;
  for (int r = 0; r < 256; ++r){
    float pos = (float)r * (127.0f/255.0f);
    int i0 = (int)pos; float w = pos - (float)i0; int i1 = min(i0+1,127);
    if (i0 == i) s += 1.0f - w;
    if (i1 == i) s += w;
  }
  wr[i] = s;
}

// ---------------- K1: weighted GAP  g[b,c] = mean of upsampled image ----------------
__global__ void k_gap(const float* __restrict__ x, const float* __restrict__ wr,
                      float* __restrict__ g){
  __shared__ float w[128];
  __shared__ float partial[4];
  int tid = threadIdx.x;
  if (tid < 128) w[tid] = wr[tid];
  __syncthreads();
  const float* xp = x + ((size_t)blockIdx.x << 14);   // blockIdx = b*64+c
  float s = 0.f;
  for (int idx = tid; idx < 16384; idx += 256){
    int i = idx >> 7, j = idx & 127;
    s += xp[idx] * w[i] * w[j];
  }
  for (int off = 32; off > 0; off >>= 1) s += __shfl_down(s, off, 64);
  if ((tid & 63) == 0) partial[tid >> 6] = s;
  __syncthreads();
  if (tid == 0) g[blockIdx.x] = (partial[0]+partial[1]+partial[2]+partial[3]) * (1.0f/65536.0f);
}

// ---------------- K2: attention MLP (single block) ----------------
__global__ void k_att(const float* __restrict__ g,
                      const float* __restrict__ fc_w,
                      const float* __restrict__ bga, const float* __restrict__ bba,
                      const float* __restrict__ bma, const float* __restrict__ bva,
                      const float* __restrict__ ch_w, const float* __restrict__ ch_b,
                      const float* __restrict__ fil_w, const float* __restrict__ fil_b,
                      const float* __restrict__ sp_w, const float* __restrict__ sp_b,
                      const float* __restrict__ k_w, const float* __restrict__ k_b,
                      const float* __restrict__ bn_g, const float* __restrict__ bn_b,
                      const float* __restrict__ bn_m, const float* __restrict__ bn_v,
                      float* __restrict__ ch_att, float* __restrict__ sp_att,
                      float* __restrict__ k_att_o, float* __restrict__ sS, float* __restrict__ tT)
{
  __shared__ float h[8][16];
  int tid = threadIdx.x;
  if (tid < 128){
    int b = tid >> 4, a = tid & 15;
    float acc = 0.f;
    for (int c = 0; c < 64; ++c) acc += g[b*64+c] * fc_w[a*64+c];
    float v = (acc - bma[a]) * rsqrtf(bva[a] + EPSBN) * bga[a] + bba[a];
    h[b][a] = fmaxf(v, 0.f);
  }
  __syncthreads();
  for (int i = tid; i < 512; i += 256){
    int b = i >> 6, c = i & 63;
    float z = ch_b[c];
    for (int a = 0; a < 16; ++a) z += h[b][a]*ch_w[c*16+a];
    ch_att[i] = 1.f/(1.f+expf(-z));
  }
  {
    int b = tid >> 5, o = tid & 31;
    float z = fil_b[o];
    for (int a = 0; a < 16; ++a) z += h[b][a]*fil_w[o*16+a];
    float f = 1.f/(1.f+expf(-z));
    float inv = rsqrtf(bn_v[o] + EPSBN);
    sS[tid] = f * bn_g[o] * inv;
    if (b == 0) tT[o] = bn_b[o] - bn_m[o] * bn_g[o] * inv;
  }
  if (tid < 72){
    int b = tid / 9, s = tid % 9;
    float z = sp_b[s];
    for (int a = 0; a < 16; ++a) z += h[b][a]*sp_w[s*16+a];
    sp_att[tid] = 1.f/(1.f+expf(-z));
  }
  if (tid < 8){
    int b = tid;
    float z0 = k_b[0], z1 = k_b[1];
    for (int a = 0; a < 16; ++a){ z0 += h[b][a]*k_w[a]; z1 += h[b][a]*k_w[16+a]; }
    float m = fmaxf(z0, z1);
    float e0 = expf(z0-m), e1 = expf(z1-m), inv = 1.f/(e0+e1);
    k_att_o[b*2]   = e0*inv;
    k_att_o[b*2+1] = e1*inv;
  }
}

// ---------------- K3: per-sample aggregated filters, layout [b][ci][9][o] ----------------
__global__ void k_aggw(const float* __restrict__ weight, const float* __restrict__ ch_att,
                       const float* __restrict__ sp_att, const float* __restrict__ ka,
                       float* __restrict__ agg)
{
  int idx = blockIdx.x*256 + threadIdx.x;     // < 147456
  int o  = idx & 31;
  int s  = (idx >> 5) % 9;
  int t  = idx / 288;                          // b*64 + ci
  int ci = t & 63, b = t >> 6;
  float w0 = weight[((0*32+o)*64+ci)*9+s];
  float w1 = weight[((1*32+o)*64+ci)*9+s];
  agg[idx] = ch_att[b*64+ci] * sp_att[b*9+s] * (ka[b*2]*w0 + ka[b*2+1]*w1);
}

// ---------------- K4: dynamic 3x3 conv on bilinearly-upsampled input + BN + GELU ----
// tile: 8 rows x 32 cols of output (256-res), all 32 Cout. 256 threads:
//   og = tid>>6 (8 couts), pg = tid&63 -> r = pg>>3, c4 = (pg&7)*4 (4 pixels)
// Upsample fused into LDS staging (per-tile interp tables + cached global loads).
__global__ __launch_bounds__(256) void k_conv(const float* __restrict__ x,
                                              const float* __restrict__ agg,
                                              const float* __restrict__ sS,
                                              const float* __restrict__ tT,
                                              float* __restrict__ out)
{
  __shared__ float xt[8][10][40];   // [ci][row(10)][col(34,pad40)]
  __shared__ float wt[8][9][32];    // [ci][s][o]
  __shared__ int   ri0[10], ri1[10], cj0[34], cj1[34];
  __shared__ float rwh[10], cww[34];

  int tid = threadIdx.x;
  int bi  = blockIdx.x;
  int b   = bi >> 8;
  int t   = bi & 255;
  int tr = t >> 3, tc = t & 7;
  int p0 = tr * 8, q0 = tc * 32;
  int og = tid >> 6;
  int pg = tid & 63;
  int r  = pg >> 3;
  int c4 = (pg & 7) * 4;

  // interp tables for the 10 tile rows / 34 tile cols (output-space p0-1.., q0-1..)
  if (tid < 10){
    int p = p0 - 1 + tid;
    if ((unsigned)p < 256u){
      float pos = (float)p * (127.0f/255.0f);
      int i0 = (int)pos;
      ri0[tid] = i0; ri1[tid] = min(i0+1,127); rwh[tid] = pos - (float)i0;
    } else { ri0[tid] = -1; ri1[tid] = 0; rwh[tid] = 0.f; }
  }
  if (tid < 34){
    int q = q0 - 1 + tid;
    if ((unsigned)q < 256u){
      float pos = (float)q * (127.0f/255.0f);
      int j0 = (int)pos;
      cj0[tid] = j0; cj1[tid] = min(j0+1,127); cww[tid] = pos - (float)j0;
    } else { cj0[tid] = -1; cj1[tid] = 0; cww[tid] = 0.f; }
  }

  float acc[8][4];
  #pragma unroll
  for (int o=0;o<8;++o){
    #pragma unroll
    for (int u=0;u<4;++u) acc[o][u]=0.f;
  }

  const float* wb = agg + b * (64*9*32);

  for (int cc = 0; cc < 8; ++cc){
    __syncthreads();
    // stage input tile: 8 ci x 10 rows x 34 cols, bilinear from 128-res input
    for (int e = tid; e < 2720; e += 256){
      int ci  = e / 340;
      int rem = e - ci*340;
      int row = rem / 34;
      int col = rem - row*34;
      float v = 0.f;
      int i0 = ri0[row], j0 = cj0[col];
      if (i0 >= 0 && j0 >= 0){
        int i1 = ri1[row], j1 = cj1[col];
        float wh = rwh[row], ww = cww[col];
        const float* xp = x + (((size_t)(b*64 + cc*8 + ci)) << 14);
        float v00 = xp[(i0<<7)+j0], v01 = xp[(i0<<7)+j1];
        float v10 = xp[(i1<<7)+j0], v11 = xp[(i1<<7)+j1];
        float a0 = v00*(1.f-ww) + v01*ww;
        float a1 = v10*(1.f-ww) + v11*ww;
        v = a0*(1.f-wh) + a1*wh;
      }
      xt[ci][row][col] = v;
    }
    // stage weights: contiguous 2304 floats
    {
      const float* src = wb + cc*(8*9*32);
      float* dst = &wt[0][0][0];
      for (int e = tid; e < 2304; e += 256) dst[e] = src[e];
    }
    __syncthreads();
    #pragma unroll
    for (int ci = 0; ci < 8; ++ci){
      #pragma unroll
      for (int ky = 0; ky < 3; ++ky){
        const float* xrow = &xt[ci][r+ky][c4];
        float px[6];
        #pragma unroll
        for (int u = 0; u < 6; ++u) px[u] = xrow[u];
        #pragma unroll
        for (int kx = 0; kx < 3; ++kx){
          const float4* wp = (const float4*)&wt[ci][ky*3+kx][og*8];
          float4 w0 = wp[0], w1 = wp[1];
          float wv[8] = {w0.x,w0.y,w0.z,w0.w,w1.x,w1.y,w1.z,w1.w};
          #pragma unroll
          for (int o = 0; o < 8; ++o){
            #pragma unroll
            for (int u = 0; u < 4; ++u)
              acc[o][u] = fmaf(wv[o], px[u+kx], acc[o][u]);
          }
        }
      }
    }
  }
  // epilogue: y = acc*s + t ; GELU(exact erf) ; store float4
  #pragma unroll
  for (int o = 0; o < 8; ++o){
    int oo = og*8 + o;
    float sv = sS[b*32+oo], tv = tT[oo];
    float4 res;
    float vv[4];
    #pragma unroll
    for (int u = 0; u < 4; ++u){
      float v = acc[o][u]*sv + tv;
      vv[u] = 0.5f*v*(1.f + erff(v*0.70710678118f));
    }
    res.x = vv[0]; res.y = vv[1]; res.z = vv[2]; res.w = vv[3];
    size_t oidx = (((size_t)(b*32+oo)) << 16) + (size_t)((p0 + r) << 8) + (size_t)(q0 + c4);
    *(float4*)&out[oidx] = res;
  }
}

extern "C" void kernel_launch(void* const* d_in, const int* in_sizes, int n_in,
                              void* d_out, int out_size, void* d_ws, size_t ws_size,
                              hipStream_t stream)
{
  const float* x     = (const float*)d_in[0];
  const float* fc_w  = (const float*)d_in[1];
  const float* bga   = (const float*)d_in[2];
  const float* bba   = (const float*)d_in[3];
  const float* bma   = (const float*)d_in[4];
  const float* bva   = (const float*)d_in[5];
  const float* ch_w  = (const float*)d_in[6];
  const float* ch_b  = (const float*)d_in[7];
  const float* fil_w = (const float*)d_in[8];
  const float* fil_b = (const float*)d_in[9];
  const float* sp_w  = (const float*)d_in[10];
  const float* sp_b  = (const float*)d_in[11];
  const float* k_w   = (const float*)d_in[12];
  const float* k_b   = (const float*)d_in[13];
  const float* weight= (const float*)d_in[14];
  const float* bn_g  = (const float*)d_in[15];
  const float* bn_b  = (const float*)d_in[16];
  const float* bn_m  = (const float*)d_in[17];
  const float* bn_v  = (const float*)d_in[18];

  char* ws = (char*)d_ws;
  float* wr    = (float*)(ws + WS_WR);
  float* g     = (float*)(ws + WS_G);
  float* ch    = (float*)(ws + WS_CH);
  float* sp    = (float*)(ws + WS_SP);
  float* ka    = (float*)(ws + WS_KA);
  float* sS    = (float*)(ws + WS_S);
  float* tT    = (float*)(ws + WS_T);
  float* agg   = (float*)(ws + WS_AGG);
  float* out   = (float*)d_out;

  hipLaunchKernelGGL(k_wr,   dim3(1),    dim3(128), 0, stream, wr);
  hipLaunchKernelGGL(k_gap,  dim3(512),  dim3(256), 0, stream, x, wr, g);
  hipLaunchKernelGGL(k_att,  dim3(1),    dim3(256), 0, stream, g, fc_w, bga, bba, bma, bva,
                     ch_w, ch_b, fil_w, fil_b, sp_w, sp_b, k_w, k_b,
                     bn_g, bn_b, bn_m, bn_v, ch, sp, ka, sS, tT);
  hipLaunchKernelGGL(k_aggw, dim3(576),  dim3(256), 0, stream, weight, ch, sp, ka, agg);
  hipLaunchKernelGGL(k_conv, dim3(2048), dim3(256), 0, stream, x, agg, sS, tT, out);
}

// Round 3
// 221.623 us; speedup vs baseline: 1.9750x; 1.9750x over previous
//
#include <hip/hip_runtime.h>
#include <hip/hip_bf16.h>

#define EPSBN 1e-5f

typedef short short8 __attribute__((ext_vector_type(8)));
typedef float f32x16 __attribute__((ext_vector_type(16)));

static __device__ __forceinline__ unsigned short f2u(float f){
  __hip_bfloat16 h = __float2bfloat16(f);
  union { __hip_bfloat16 h; unsigned short u; } c; c.h = h; return c.u;
}

// ---- workspace layout (bytes) ----
#define WS_WR    0
#define WS_G     2048
#define WS_CH    4096
#define WS_SP    6144
#define WS_KA    6656
#define WS_S     7168
#define WS_T     8192
#define WS_AGGB  16384      // 147456 bf16  [b][cc4][s9][o32][ci16]
#define WS_XUP   327680     // 33554432 bf16 [b][cc4][r256][c256][ci16]

// ---------------- K0: per-input-row total bilinear weights Wr[128] ----------------
__global__ void k_wr(float* __restrict__ wr){
  int i = threadIdx.x;
  float s = 0.f;
  for (int r = 0; r < 256; ++r){
    float pos = (float)r * (127.0f/255.0f);
    int i0 = (int)pos; float w = pos - (float)i0; int i1 = min(i0+1,127);
    if (i0 == i) s += 1.0f - w;
    if (i1 == i) s += w;
  }
  wr[i] = s;
}

// ---------------- K1: weighted GAP ----------------
__global__ void k_gap(const float* __restrict__ x, const float* __restrict__ wr,
                      float* __restrict__ g){
  __shared__ float w[128];
  __shared__ float partial[4];
  int tid = threadIdx.x;
  if (tid < 128) w[tid] = wr[tid];
  __syncthreads();
  const float* xp = x + ((size_t)blockIdx.x << 14);
  float s = 0.f;
  for (int idx = tid; idx < 16384; idx += 256){
    int i = idx >> 7, j = idx & 127;
    s += xp[idx] * w[i] * w[j];
  }
  for (int off = 32; off > 0; off >>= 1) s += __shfl_down(s, off, 64);
  if ((tid & 63) == 0) partial[tid >> 6] = s;
  __syncthreads();
  if (tid == 0) g[blockIdx.x] = (partial[0]+partial[1]+partial[2]+partial[3]) * (1.0f/65536.0f);
}

// ---------------- K2: attention MLP ----------------
__global__ void k_att(const float* __restrict__ g,
                      const float* __restrict__ fc_w,
                      const float* __restrict__ bga, const float* __restrict__ bba,
                      const float* __restrict__ bma, const float* __restrict__ bva,
                      const float* __restrict__ ch_w, const float* __restrict__ ch_b,
                      const float* __restrict__ fil_w, const float* __restrict__ fil_b,
                      const float* __restrict__ sp_w, const float* __restrict__ sp_b,
                      const float* __restrict__ k_w, const float* __restrict__ k_b,
                      const float* __restrict__ bn_g, const float* __restrict__ bn_b,
                      const float* __restrict__ bn_m, const float* __restrict__ bn_v,
                      float* __restrict__ ch_att, float* __restrict__ sp_att,
                      float* __restrict__ k_att_o, float* __restrict__ sS, float* __restrict__ tT)
{
  __shared__ float h[8][16];
  int tid = threadIdx.x;
  if (tid < 128){
    int b = tid >> 4, a = tid & 15;
    float acc = 0.f;
    for (int c = 0; c < 64; ++c) acc += g[b*64+c] * fc_w[a*64+c];
    float v = (acc - bma[a]) * rsqrtf(bva[a] + EPSBN) * bga[a] + bba[a];
    h[b][a] = fmaxf(v, 0.f);
  }
  __syncthreads();
  for (int i = tid; i < 512; i += 256){
    int b = i >> 6, c = i & 63;
    float z = ch_b[c];
    for (int a = 0; a < 16; ++a) z += h[b][a]*ch_w[c*16+a];
    ch_att[i] = 1.f/(1.f+expf(-z));
  }
  {
    int b = tid >> 5, o = tid & 31;
    float z = fil_b[o];
    for (int a = 0; a < 16; ++a) z += h[b][a]*fil_w[o*16+a];
    float f = 1.f/(1.f+expf(-z));
    float inv = rsqrtf(bn_v[o] + EPSBN);
    sS[tid] = f * bn_g[o] * inv;
    if (b == 0) tT[o] = bn_b[o] - bn_m[o] * bn_g[o] * inv;
  }
  if (tid < 72){
    int b = tid / 9, s = tid % 9;
    float z = sp_b[s];
    for (int a = 0; a < 16; ++a) z += h[b][a]*sp_w[s*16+a];
    sp_att[tid] = 1.f/(1.f+expf(-z));
  }
  if (tid < 8){
    int b = tid;
    float z0 = k_b[0], z1 = k_b[1];
    for (int a = 0; a < 16; ++a){ z0 += h[b][a]*k_w[a]; z1 += h[b][a]*k_w[16+a]; }
    float m = fmaxf(z0, z1);
    float e0 = expf(z0-m), e1 = expf(z1-m), inv = 1.f/(e0+e1);
    k_att_o[b*2]   = e0*inv;
    k_att_o[b*2+1] = e1*inv;
  }
}

// -------- K3: aggregated filters -> bf16, layout [b][cc4][s9][o32][ci16] --------
__global__ void k_aggw(const float* __restrict__ weight, const float* __restrict__ ch_att,
                       const float* __restrict__ sp_att, const float* __restrict__ ka,
                       unsigned short* __restrict__ aggb)
{
  int idx = blockIdx.x*256 + threadIdx.x;     // < 147456
  int ci_l = idx & 15;
  int o    = (idx >> 4) & 31;
  int s    = (idx >> 9) % 9;
  int t2   = idx / 4608;
  int cc   = t2 & 3, b = t2 >> 2;
  int ci   = cc*16 + ci_l;
  float w0 = weight[(o*64+ci)*9+s];
  float w1 = weight[((32+o)*64+ci)*9+s];
  float v  = ch_att[b*64+ci] * sp_att[b*9+s] * (ka[b*2]*w0 + ka[b*2+1]*w1);
  aggb[idx] = f2u(v);
}

// -------- K4: bilinear x2 upsample -> bf16 [b][cc][r][c][ci16] --------
// grid: 1024 = b(8) x cc(4) x strip(32 of 8 rows)
__global__ __launch_bounds__(256) void k_up(const float* __restrict__ x,
                                            unsigned int* __restrict__ xup32)
{
  __shared__ float xin[16*6*133];     // [ci][ir][j] padded
  int tid = threadIdx.x;
  int bi  = blockIdx.x;
  int strip = bi & 31, cc = (bi >> 5) & 3, b = bi >> 7;
  int r0 = strip * 8;
  int i0b = (int)((float)r0 * (127.0f/255.0f));

  // load 6 input rows x 16 ci (row-clamped)
  for (int e = tid; e < 12288; e += 256){
    int ir = e >> 11;
    int rem = e & 2047;
    int ci = rem >> 7;
    int j  = rem & 127;
    int row = min(i0b + ir, 127);
    xin[ci*798 + ir*133 + j] = x[(((size_t)(b*64 + cc*16 + ci)) << 14) + (row << 7) + j];
  }
  __syncthreads();

  for (int e2 = tid; e2 < 16384; e2 += 256){
    int ci2 = e2 & 7;            // ci pair
    int c   = (e2 >> 3) & 255;
    int rr  = e2 >> 11;          // 0..7
    int r   = r0 + rr;
    float posr = (float)r * (127.0f/255.0f);
    int i0g = (int)posr; float wh = posr - (float)i0g;
    int i1g = min(i0g+1, 127);
    int ir0 = i0g - i0b, ir1 = i1g - i0b;
    float posc = (float)c * (127.0f/255.0f);
    int j0 = (int)posc; float ww = posc - (float)j0;
    int j1 = min(j0+1, 127);
    unsigned int pack = 0;
    #pragma unroll
    for (int u = 0; u < 2; ++u){
      int ci = ci2*2 + u;
      const float* base = &xin[ci*798];
      float v00 = base[ir0*133 + j0], v01 = base[ir0*133 + j1];
      float v10 = base[ir1*133 + j0], v11 = base[ir1*133 + j1];
      float a0 = v00 + (v01 - v00)*ww;
      float a1 = v10 + (v11 - v10)*ww;
      float v  = a0 + (a1 - a0)*wh;
      pack |= ((unsigned int)f2u(v)) << (16*u);
    }
    size_t idx = ((((size_t)(b*4+cc)*256 + r)*256 + c) << 4) + ci2*2;
    xup32[idx >> 1] = pack;
  }
}

// -------- K5: MFMA implicit-GEMM conv + BN + GELU --------
// block: 16x16 output px, all 32 Cout. 4 waves, each 2 tiles of (32 o x 32 px).
__global__ __launch_bounds__(256) void k_conv(const unsigned short* __restrict__ xup,
                                              const unsigned short* __restrict__ aggb,
                                              const float* __restrict__ sS,
                                              const float* __restrict__ tT,
                                              float* __restrict__ out)
{
  __shared__ unsigned short xt[18*18*24];   // [rr][qq][ci24pad]
  __shared__ unsigned short wt[288*24];     // [s*32+o][ci24pad]
  __shared__ float sSs[32], tTs[32];

  int tid = threadIdx.x;
  int bi  = blockIdx.x;
  int b   = bi >> 8, t = bi & 255;
  int p0  = (t >> 4) * 16, q0 = (t & 15) * 16;
  int lane = tid & 63, wv = tid >> 6;
  if (tid < 32){ sSs[tid] = sS[b*32+tid]; tTs[tid] = tT[tid]; }

  f32x16 acc[2];
  #pragma unroll
  for (int i = 0; i < 16; ++i){ acc[0][i] = 0.f; acc[1][i] = 0.f; }

  int n  = lane & 31;
  int kq = lane >> 5;

  for (int cc = 0; cc < 4; ++cc){
    if (cc) __syncthreads();
    // stage input tile 18x18x16ci (16B granules)
    for (int e = tid; e < 648; e += 256){
      int rr  = e / 36;
      int rem = e - rr*36;
      int qq  = rem >> 1;
      int half= rem & 1;
      int gr = p0 - 1 + rr, gq = q0 - 1 + qq;
      short8 v = {0,0,0,0,0,0,0,0};
      if ((unsigned)gr < 256u && (unsigned)gq < 256u){
        size_t gidx = ((((size_t)(b*4+cc)*256 + gr)*256 + gq) << 4) + half*8;
        v = *(const short8*)&xup[gidx];
      }
      *(short8*)&xt[(rr*18+qq)*24 + half*8] = v;
    }
    // stage weights 9x32x16ci
    for (int e = tid; e < 576; e += 256){
      int so = e >> 1, half = e & 1;
      size_t gidx = (((size_t)(b*4+cc)*288 + so) << 4) + half*8;
      *(short8*)&wt[so*24 + half*8] = *(const short8*)&aggb[gidx];
    }
    __syncthreads();

    #pragma unroll
    for (int s = 0; s < 9; ++s){
      const int ky = s / 3, kx = s % 3;
      short8 av = *(const short8*)&wt[(s*32 + n)*24 + kq*8];
      #pragma unroll
      for (int tt = 0; tt < 2; ++tt){
        int lr = 2*(2*wv + tt) + (n >> 4);
        int rr = lr + ky;
        int qq = (n & 15) + kx;
        short8 bv = *(const short8*)&xt[(rr*18+qq)*24 + kq*8];
        acc[tt] = __builtin_amdgcn_mfma_f32_32x32x16_bf16(av, bv, acc[tt], 0, 0, 0);
      }
    }
  }

  // epilogue: scale/bias + GELU(exact erf), fp32 stores
  #pragma unroll
  for (int tt = 0; tt < 2; ++tt){
    int lr = 2*(2*wv + tt) + (n >> 4);
    int p = p0 + lr, q = q0 + (n & 15);
    #pragma unroll
    for (int r = 0; r < 16; ++r){
      int o = (r & 3) + 8*(r >> 2) + 4*kq;
      float val = acc[tt][r]*sSs[o] + tTs[o];
      float gl  = 0.5f*val*(1.f + erff(val*0.70710678118f));
      out[(((size_t)(b*32+o)) << 16) + (p << 8) + q] = gl;
    }
  }
}

extern "C" void kernel_launch(void* const* d_in, const int* in_sizes, int n_in,
                              void* d_out, int out_size, void* d_ws, size_t ws_size,
                              hipStream_t stream)
{
  const float* x     = (const float*)d_in[0];
  const float* fc_w  = (const float*)d_in[1];
  const float* bga   = (const float*)d_in[2];
  const float* bba   = (const float*)d_in[3];
  const float* bma   = (const float*)d_in[4];
  const float* bva   = (const float*)d_in[5];
  const float* ch_w  = (const float*)d_in[6];
  const float* ch_b  = (const float*)d_in[7];
  const float* fil_w = (const float*)d_in[8];
  const float* fil_b = (const float*)d_in[9];
  const float* sp_w  = (const float*)d_in[10];
  const float* sp_b  = (const float*)d_in[11];
  const float* k_w   = (const float*)d_in[12];
  const float* k_b   = (const float*)d_in[13];
  const float* weight= (const float*)d_in[14];
  const float* bn_g  = (const float*)d_in[15];
  const float* bn_b  = (const float*)d_in[16];
  const float* bn_m  = (const float*)d_in[17];
  const float* bn_v  = (const float*)d_in[18];

  char* ws = (char*)d_ws;
  float* wr  = (float*)(ws + WS_WR);
  float* g   = (float*)(ws + WS_G);
  float* ch  = (float*)(ws + WS_CH);
  float* sp  = (float*)(ws + WS_SP);
  float* ka  = (float*)(ws + WS_KA);
  float* sS  = (float*)(ws + WS_S);
  float* tT  = (float*)(ws + WS_T);
  unsigned short* aggb = (unsigned short*)(ws + WS_AGGB);
  unsigned short* xup  = (unsigned short*)(ws + WS_XUP);
  float* out = (float*)d_out;

  hipLaunchKernelGGL(k_wr,   dim3(1),    dim3(128), 0, stream, wr);
  hipLaunchKernelGGL(k_gap,  dim3(512),  dim3(256), 0, stream, x, wr, g);
  hipLaunchKernelGGL(k_att,  dim3(1),    dim3(256), 0, stream, g, fc_w, bga, bba, bma, bva,
                     ch_w, ch_b, fil_w, fil_b, sp_w, sp_b, k_w, k_b,
                     bn_g, bn_b, bn_m, bn_v, ch, sp, ka, sS, tT);
  hipLaunchKernelGGL(k_aggw, dim3(576),  dim3(256), 0, stream, weight, ch, sp, ka, aggb);
  hipLaunchKernelGGL(k_up,   dim3(1024), dim3(256), 0, stream, x, (unsigned int*)xup);
  hipLaunchKernelGGL(k_conv, dim3(2048), dim3(256), 0, stream, xup, aggb, sS, tT, out);
}

// Round 4
// 206.867 us; speedup vs baseline: 2.1159x; 1.0713x over previous
//
#include <hip/hip_runtime.h>
#include <hip/hip_bf16.h>

#define EPSBN 1e-5f

typedef short short8 __attribute__((ext_vector_type(8)));
typedef float f32x16 __attribute__((ext_vector_type(16)));

static __device__ __forceinline__ unsigned short f2u(float f){
  __hip_bfloat16 h = __float2bfloat16(f);
  union { __hip_bfloat16 h; unsigned short u; } c; c.h = h; return c.u;
}

// ---- workspace layout (bytes) ----
#define WS_G     2048
#define WS_S     7168
#define WS_T     8192
#define WS_AGGB  16384      // 147456 bf16  [b][cc4][s9][o32][ci16]

// ---------------- K1: weighted GAP (row-weight table computed inline) ----------------
__global__ __launch_bounds__(256) void k_gap(const float* __restrict__ x, float* __restrict__ g){
  __shared__ float w[128];
  __shared__ float partial[4];
  int tid = threadIdx.x;
  if (tid < 128){
    int i = tid;
    float s = 0.f;
    int rstart = max(0, (int)floorf((float)(i-1)*(255.0f/127.0f)));
    #pragma unroll
    for (int k = 0; k < 8; ++k){
      int r = rstart + k;
      if (r <= 255){
        float pos = (float)r * (127.0f/255.0f);
        int i0 = (int)pos; float fr = pos - (float)i0; int i1 = min(i0+1,127);
        if (i0 == i) s += 1.0f - fr;
        if (i1 == i) s += fr;
      }
    }
    w[i] = s;
  }
  __syncthreads();
  const float4* xp = (const float4*)(x + ((size_t)blockIdx.x << 14));
  float s = 0.f;
  for (int gi = tid; gi < 4096; gi += 256){
    int i = gi >> 5, j4 = (gi & 31) * 4;
    float4 v = xp[gi];
    s += (v.x*w[j4] + v.y*w[j4+1] + v.z*w[j4+2] + v.w*w[j4+3]) * w[i];
  }
  for (int off = 32; off > 0; off >>= 1) s += __shfl_down(s, off, 64);
  if ((tid & 63) == 0) partial[tid >> 6] = s;
  __syncthreads();
  if (tid == 0) g[blockIdx.x] = (partial[0]+partial[1]+partial[2]+partial[3]) * (1.0f/65536.0f);
}

// ------- K2: attention MLP (redundant per block) + aggregated bf16 filters -------
// layout out: [b][cc4][s9][o32][ci16]
__global__ __launch_bounds__(256) void k_aggw(const float* __restrict__ g,
                      const float* __restrict__ fc_w,
                      const float* __restrict__ bga, const float* __restrict__ bba,
                      const float* __restrict__ bma, const float* __restrict__ bva,
                      const float* __restrict__ ch_w, const float* __restrict__ ch_b,
                      const float* __restrict__ fil_w, const float* __restrict__ fil_b,
                      const float* __restrict__ sp_w, const float* __restrict__ sp_b,
                      const float* __restrict__ k_w, const float* __restrict__ k_b,
                      const float* __restrict__ bn_g, const float* __restrict__ bn_b,
                      const float* __restrict__ bn_m, const float* __restrict__ bn_v,
                      const float* __restrict__ weight,
                      unsigned short* __restrict__ aggb,
                      float* __restrict__ sS, float* __restrict__ tT)
{
  __shared__ float h[8][16];
  int tid = threadIdx.x;
  if (tid < 128){
    int b = tid >> 4, a = tid & 15;
    float acc = 0.f;
    for (int c = 0; c < 64; ++c) acc += g[b*64+c] * fc_w[a*64+c];
    float v = (acc - bma[a]) * rsqrtf(bva[a] + EPSBN) * bga[a] + bba[a];
    h[b][a] = fmaxf(v, 0.f);
  }
  __syncthreads();

  int idx = blockIdx.x*256 + tid;      // < 147456
  int ci_l = idx & 15;
  int o    = (idx >> 4) & 31;
  int s    = (idx >> 9) % 9;
  int t2   = idx / 4608;
  int cc   = t2 & 3, b = t2 >> 2;
  int ci   = cc*16 + ci_l;

  const float* hb = h[b];
  float zc = ch_b[ci], zs = sp_b[s];
  float z0 = k_b[0],  z1 = k_b[1];
  #pragma unroll
  for (int a = 0; a < 16; ++a){
    float hv = hb[a];
    zc += hv*ch_w[ci*16+a];
    zs += hv*sp_w[s*16+a];
    z0 += hv*k_w[a];
    z1 += hv*k_w[16+a];
  }
  float chv = 1.f/(1.f+expf(-zc));
  float spv = 1.f/(1.f+expf(-zs));
  float m = fmaxf(z0,z1);
  float e0 = expf(z0-m), e1 = expf(z1-m), inv = 1.f/(e0+e1);
  float ka0 = e0*inv, ka1 = e1*inv;
  float w0 = weight[(o*64+ci)*9+s];
  float w1 = weight[((32+o)*64+ci)*9+s];
  aggb[idx] = f2u(chv*spv*(ka0*w0 + ka1*w1));

  if (blockIdx.x == 0){
    int bb = tid >> 5, oo = tid & 31;
    float z = fil_b[oo];
    #pragma unroll
    for (int a = 0; a < 16; ++a) z += h[bb][a]*fil_w[oo*16+a];
    float f = 1.f/(1.f+expf(-z));
    float invs = rsqrtf(bn_v[oo] + EPSBN);
    sS[tid] = f * bn_g[oo] * invs;
    if (bb == 0) tT[oo] = bn_b[oo] - bn_m[oo]*bn_g[oo]*invs;
  }
}

// -------- K3: MFMA implicit-GEMM conv, upsample fused into staging, + BN + GELU ----
// block: 16x16 output px, all 32 Cout. 4 waves, each 2 tiles of (32 o x 32 px).
__global__ __launch_bounds__(256) void k_conv(const float* __restrict__ x,
                                              const unsigned short* __restrict__ aggb,
                                              const float* __restrict__ sS,
                                              const float* __restrict__ tT,
                                              float* __restrict__ out)
{
  __shared__ unsigned short xt[18*18*24];   // [rr][qq][ci24pad] bf16
  __shared__ unsigned short wt[288*24];     // [s*32+o][ci24pad] bf16
  __shared__ float xin[16*121];             // [ci][ir10][jj12] fp32 (stride 121 vs 120: bank spread)
  __shared__ int   ir0s[18], ir1s[18], jc0s[18], jc1s[18];
  __shared__ float rwhs[18], cwws[18];
  __shared__ float sSs[32], tTs[32];

  int tid = threadIdx.x;
  int bi  = blockIdx.x;
  int b   = bi >> 8, t = bi & 255;
  int p0  = (t >> 4) * 16, q0 = (t & 15) * 16;
  int lane = tid & 63, wv = tid >> 6;
  if (tid < 32){ sSs[tid] = sS[b*32+tid]; tTs[tid] = tT[tid]; }

  int i0b = (int)((float)max(p0-1,0) * (127.0f/255.0f));
  int j0b = (int)((float)max(q0-1,0) * (127.0f/255.0f));

  if (tid < 18){
    int gr = p0 - 1 + tid;
    if ((unsigned)gr < 256u){
      float pos = (float)gr * (127.0f/255.0f);
      int i0 = (int)pos;
      ir0s[tid] = i0 - i0b;
      ir1s[tid] = min(i0+1,127) - i0b;
      rwhs[tid] = pos - (float)i0;
    } else { ir0s[tid] = -1000; ir1s[tid] = 0; rwhs[tid] = 0.f; }
  } else if (tid < 36){
    int k = tid - 18;
    int gq = q0 - 1 + k;
    if ((unsigned)gq < 256u){
      float pos = (float)gq * (127.0f/255.0f);
      int j0 = (int)pos;
      jc0s[k] = j0 - j0b;
      jc1s[k] = min(j0+1,127) - j0b;
      cwws[k] = pos - (float)j0;
    } else { jc0s[k] = -1000; jc1s[k] = 0; cwws[k] = 0.f; }
  }

  f32x16 acc[2];
  #pragma unroll
  for (int i = 0; i < 16; ++i){ acc[0][i] = 0.f; acc[1][i] = 0.f; }

  int n  = lane & 31;
  int kq = lane >> 5;

  for (int cc = 0; cc < 4; ++cc){
    __syncthreads();
    // stage 128-res source region: 16 ci x 10 rows x 12 cols fp32 (clamped)
    {
      const float* xb = x + (((size_t)(b*64 + cc*16)) << 14);
      for (int e = tid; e < 1920; e += 256){
        int ci  = e / 120;
        int rem = e - ci*120;
        int ir  = rem / 12;
        int jj  = rem - ir*12;
        int row = min(i0b + ir, 127);
        int col = min(j0b + jj, 127);
        xin[ci*121 + rem] = xb[((size_t)ci << 14) + (row << 7) + col];
      }
    }
    // stage weights 9x32x16ci (576 granules of 16B)
    for (int e = tid; e < 576; e += 256){
      int so = e >> 1, half = e & 1;
      size_t gidx = (((size_t)(b*4+cc)*288 + so) << 4) + half*8;
      *(short8*)&wt[so*24 + half*8] = *(const short8*)&aggb[gidx];
    }
    __syncthreads();
    // bilinear upsample interp -> bf16 MFMA tile
    for (int e = tid; e < 5184; e += 256){
      int ci   = e & 15;
      int rest = e >> 4;        // < 324
      int rr   = rest / 18;
      int qq   = rest - rr*18;
      unsigned short uv = 0;
      int i0 = ir0s[rr], j0 = jc0s[qq];
      if (i0 >= 0 && j0 >= 0){
        int i1 = ir1s[rr], j1 = jc1s[qq];
        float wh = rwhs[rr], ww = cwws[qq];
        const float* base = &xin[ci*121];
        float v00 = base[i0*12+j0], v01 = base[i0*12+j1];
        float v10 = base[i1*12+j0], v11 = base[i1*12+j1];
        float a0 = v00 + (v01 - v00)*ww;
        float a1 = v10 + (v11 - v10)*ww;
        uv = f2u(a0 + (a1 - a0)*wh);
      }
      xt[(rr*18+qq)*24 + ci] = uv;
    }
    __syncthreads();

    #pragma unroll
    for (int s = 0; s < 9; ++s){
      const int ky = s / 3, kx = s % 3;
      short8 av = *(const short8*)&wt[(s*32 + n)*24 + kq*8];
      #pragma unroll
      for (int tt = 0; tt < 2; ++tt){
        int lr = 2*(2*wv + tt) + (n >> 4);
        int rr = lr + ky;
        int qq = (n & 15) + kx;
        short8 bv = *(const short8*)&xt[(rr*18+qq)*24 + kq*8];
        acc[tt] = __builtin_amdgcn_mfma_f32_32x32x16_bf16(av, bv, acc[tt], 0, 0, 0);
      }
    }
  }

  // epilogue: scale/bias + GELU(exact erf), fp32 stores
  #pragma unroll
  for (int tt = 0; tt < 2; ++tt){
    int lr = 2*(2*wv + tt) + (n >> 4);
    int p = p0 + lr, q = q0 + (n & 15);
    #pragma unroll
    for (int r = 0; r < 16; ++r){
      int o = (r & 3) + 8*(r >> 2) + 4*kq;
      float val = acc[tt][r]*sSs[o] + tTs[o];
      float gl  = 0.5f*val*(1.f + erff(val*0.70710678118f));
      out[(((size_t)(b*32+o)) << 16) + (p << 8) + q] = gl;
    }
  }
}

extern "C" void kernel_launch(void* const* d_in, const int* in_sizes, int n_in,
                              void* d_out, int out_size, void* d_ws, size_t ws_size,
                              hipStream_t stream)
{
  const float* x     = (const float*)d_in[0];
  const float* fc_w  = (const float*)d_in[1];
  const float* bga   = (const float*)d_in[2];
  const float* bba   = (const float*)d_in[3];
  const float* bma   = (const float*)d_in[4];
  const float* bva   = (const float*)d_in[5];
  const float* ch_w  = (const float*)d_in[6];
  const float* ch_b  = (const float*)d_in[7];
  const float* fil_w = (const float*)d_in[8];
  const float* fil_b = (const float*)d_in[9];
  const float* sp_w  = (const float*)d_in[10];
  const float* sp_b  = (const float*)d_in[11];
  const float* k_w   = (const float*)d_in[12];
  const float* k_b   = (const float*)d_in[13];
  const float* weight= (const float*)d_in[14];
  const float* bn_g  = (const float*)d_in[15];
  const float* bn_b  = (const float*)d_in[16];
  const float* bn_m  = (const float*)d_in[17];
  const float* bn_v  = (const float*)d_in[18];

  char* ws = (char*)d_ws;
  float* g   = (float*)(ws + WS_G);
  float* sS  = (float*)(ws + WS_S);
  float* tT  = (float*)(ws + WS_T);
  unsigned short* aggb = (unsigned short*)(ws + WS_AGGB);
  float* out = (float*)d_out;

  hipLaunchKernelGGL(k_gap,  dim3(512),  dim3(256), 0, stream, x, g);
  hipLaunchKernelGGL(k_aggw, dim3(576),  dim3(256), 0, stream, g, fc_w, bga, bba, bma, bva,
                     ch_w, ch_b, fil_w, fil_b, sp_w, sp_b, k_w, k_b,
                     bn_g, bn_b, bn_m, bn_v, weight, aggb, sS, tT);
  hipLaunchKernelGGL(k_conv, dim3(2048), dim3(256), 0, stream, x, aggb, sS, tT, out);
}

// Round 5
// 206.768 us; speedup vs baseline: 2.1169x; 1.0005x over previous
//
#include <hip/hip_runtime.h>
#include <hip/hip_bf16.h>

#define EPSBN 1e-5f

typedef short short8 __attribute__((ext_vector_type(8)));
typedef float f32x16 __attribute__((ext_vector_type(16)));

static __device__ __forceinline__ unsigned short f2u(float f){
  __hip_bfloat16 h = __float2bfloat16(f);
  union { __hip_bfloat16 h; unsigned short u; } c; c.h = h; return c.u;
}

// ---- workspace layout (bytes) ----
#define WS_G     2048
#define WS_S     7168
#define WS_T     8192
#define WS_AGGB  16384      // 147456 bf16  [b][cc2][s9][o32][ci32]
#define WS_XUP   327680     // 33554432 bf16 [b][cc2][r256][c256][ci32]

// ---------------- K1: weighted GAP (row-weight table computed inline) ----------------
__global__ __launch_bounds__(256) void k_gap(const float* __restrict__ x, float* __restrict__ g){
  __shared__ float w[128];
  __shared__ float partial[4];
  int tid = threadIdx.x;
  if (tid < 128){
    int i = tid;
    float s = 0.f;
    int rstart = max(0, (int)floorf((float)(i-1)*(255.0f/127.0f)));
    #pragma unroll
    for (int k = 0; k < 8; ++k){
      int r = rstart + k;
      if (r <= 255){
        float pos = (float)r * (127.0f/255.0f);
        int i0 = (int)pos; float fr = pos - (float)i0; int i1 = min(i0+1,127);
        if (i0 == i) s += 1.0f - fr;
        if (i1 == i) s += fr;
      }
    }
    w[i] = s;
  }
  __syncthreads();
  const float4* xp = (const float4*)(x + ((size_t)blockIdx.x << 14));
  float s = 0.f;
  for (int gi = tid; gi < 4096; gi += 256){
    int i = gi >> 5, j4 = (gi & 31) * 4;
    float4 v = xp[gi];
    s += (v.x*w[j4] + v.y*w[j4+1] + v.z*w[j4+2] + v.w*w[j4+3]) * w[i];
  }
  for (int off = 32; off > 0; off >>= 1) s += __shfl_down(s, off, 64);
  if ((tid & 63) == 0) partial[tid >> 6] = s;
  __syncthreads();
  if (tid == 0) g[blockIdx.x] = (partial[0]+partial[1]+partial[2]+partial[3]) * (1.0f/65536.0f);
}

// ------- K2: attention MLP (redundant per block) + aggregated bf16 filters -------
// layout out: [b][cc2][s9][o32][ci32]
__global__ __launch_bounds__(256) void k_aggw(const float* __restrict__ g,
                      const float* __restrict__ fc_w,
                      const float* __restrict__ bga, const float* __restrict__ bba,
                      const float* __restrict__ bma, const float* __restrict__ bva,
                      const float* __restrict__ ch_w, const float* __restrict__ ch_b,
                      const float* __restrict__ fil_w, const float* __restrict__ fil_b,
                      const float* __restrict__ sp_w, const float* __restrict__ sp_b,
                      const float* __restrict__ k_w, const float* __restrict__ k_b,
                      const float* __restrict__ bn_g, const float* __restrict__ bn_b,
                      const float* __restrict__ bn_m, const float* __restrict__ bn_v,
                      const float* __restrict__ weight,
                      unsigned short* __restrict__ aggb,
                      float* __restrict__ sS, float* __restrict__ tT)
{
  __shared__ float h[8][16];
  int tid = threadIdx.x;
  if (tid < 128){
    int b = tid >> 4, a = tid & 15;
    float acc = 0.f;
    for (int c = 0; c < 64; ++c) acc += g[b*64+c] * fc_w[a*64+c];
    float v = (acc - bma[a]) * rsqrtf(bva[a] + EPSBN) * bga[a] + bba[a];
    h[b][a] = fmaxf(v, 0.f);
  }
  __syncthreads();

  int idx = blockIdx.x*256 + tid;      // < 147456
  int ci_l = idx & 31;
  int o    = (idx >> 5) & 31;
  int s    = (idx >> 10) % 9;
  int t2   = (idx >> 10) / 9;          // b*2+cc
  int cc   = t2 & 1, b = t2 >> 1;
  int ci   = cc*32 + ci_l;

  const float* hb = h[b];
  float zc = ch_b[ci], zs = sp_b[s];
  float z0 = k_b[0],  z1 = k_b[1];
  #pragma unroll
  for (int a = 0; a < 16; ++a){
    float hv = hb[a];
    zc += hv*ch_w[ci*16+a];
    zs += hv*sp_w[s*16+a];
    z0 += hv*k_w[a];
    z1 += hv*k_w[16+a];
  }
  float chv = 1.f/(1.f+expf(-zc));
  float spv = 1.f/(1.f+expf(-zs));
  float m = fmaxf(z0,z1);
  float e0 = expf(z0-m), e1 = expf(z1-m), inv = 1.f/(e0+e1);
  float ka0 = e0*inv, ka1 = e1*inv;
  float w0 = weight[(o*64+ci)*9+s];
  float w1 = weight[((32+o)*64+ci)*9+s];
  aggb[idx] = f2u(chv*spv*(ka0*w0 + ka1*w1));

  if (blockIdx.x == 0){
    int bb = tid >> 5, oo = tid & 31;
    float z = fil_b[oo];
    #pragma unroll
    for (int a = 0; a < 16; ++a) z += h[bb][a]*fil_w[oo*16+a];
    float f = 1.f/(1.f+expf(-z));
    float invs = rsqrtf(bn_v[oo] + EPSBN);
    sS[tid] = f * bn_g[oo] * invs;
    if (bb == 0) tT[oo] = bn_b[oo] - bn_m[oo]*bn_g[oo]*invs;
  }
}

// -------- K3: bilinear x2 upsample -> bf16 [b][cc2][r][c][ci32] --------
// grid: 1024 = b(8) x h16(4: 16-ci group) x strip(32 of 8 rows)
__global__ __launch_bounds__(256) void k_up(const float* __restrict__ x,
                                            unsigned int* __restrict__ xup32)
{
  __shared__ float xin[16*798];     // [ci16][ir6][j133pad]
  int tid = threadIdx.x;
  int bi  = blockIdx.x;
  int strip = bi & 31, h16 = (bi >> 5) & 3, b = bi >> 7;
  int r0 = strip * 8;
  int i0b = (int)((float)r0 * (127.0f/255.0f));

  for (int e = tid; e < 12288; e += 256){
    int ir = e >> 11, rem = e & 2047, ci = rem >> 7, j = rem & 127;
    int row = min(i0b + ir, 127);
    xin[ci*798 + ir*133 + j] = x[(((size_t)(b*64 + h16*16 + ci)) << 14) + (row << 7) + j];
  }
  __syncthreads();

  int ci2 = tid & 7, cbase = tid >> 3;   // cbase 0..31
  int j0t[8], j1t[8]; float wwt[8];
  #pragma unroll
  for (int jj = 0; jj < 8; ++jj){
    int c = cbase + 32*jj;
    float pos = (float)c * (127.0f/255.0f);
    int j0 = (int)pos;
    j0t[jj] = j0; j1t[jj] = min(j0+1,127); wwt[jj] = pos - (float)j0;
  }
  const float* base0 = &xin[(ci2*2+0)*798];
  const float* base1 = &xin[(ci2*2+1)*798];
  size_t pxbase = ((size_t)(b*2 + (h16>>1))) << 16;   // (b*2+cc)*65536
  int halfoff = (h16 & 1)*8;

  for (int rr = 0; rr < 8; ++rr){
    int r = r0 + rr;
    float posr = (float)r * (127.0f/255.0f);
    int i0 = (int)posr; float wh = posr - (float)i0;
    int ir0 = (i0 - i0b)*133, ir1 = (min(i0+1,127) - i0b)*133;
    #pragma unroll
    for (int jj = 0; jj < 8; ++jj){
      int c = cbase + 32*jj;
      int j0 = j0t[jj], j1 = j1t[jj]; float ww = wwt[jj];
      float v00 = base0[ir0+j0], v01 = base0[ir0+j1];
      float v10 = base0[ir1+j0], v11 = base0[ir1+j1];
      float a0 = v00 + (v01-v00)*ww;
      float a1 = v10 + (v11-v10)*ww;
      float r0v = a0 + (a1-a0)*wh;
      float u00 = base1[ir0+j0], u01 = base1[ir0+j1];
      float u10 = base1[ir1+j0], u11 = base1[ir1+j1];
      float b0 = u00 + (u01-u00)*ww;
      float b1 = u10 + (u11-u10)*ww;
      float r1v = b0 + (b1-b0)*wh;
      unsigned pack = (unsigned)f2u(r0v) | (((unsigned)f2u(r1v)) << 16);
      xup32[(pxbase + (size_t)(r*256 + c))*16 + halfoff + ci2] = pack;
    }
  }
}

// -------- K4: MFMA implicit-GEMM conv + BN + GELU --------
// block: 16x16 output px, all 32 Cout; 4 waves x 2 acc tiles; 2 cc chunks of 32 ci.
#define XT_STRIDE 40   // 32 ci + 8 pad halfwords (80 B, 16B-aligned, bank-balanced)
__global__ __launch_bounds__(256) void k_conv(const unsigned short* __restrict__ xup,
                                              const unsigned short* __restrict__ aggb,
                                              const float* __restrict__ sS,
                                              const float* __restrict__ tT,
                                              float* __restrict__ out)
{
  __shared__ unsigned short xt[18*18*XT_STRIDE];   // 25920 B
  __shared__ unsigned short wt[288*XT_STRIDE];     // 23040 B
  __shared__ float sSs[32], tTs[32];

  int tid = threadIdx.x;
  int bi  = blockIdx.x;
  int b   = bi >> 8, t = bi & 255;
  int p0  = (t >> 4) * 16, q0 = (t & 15) * 16;
  int lane = tid & 63, wv = tid >> 6;
  if (tid < 32){ sSs[tid] = sS[b*32+tid]; tTs[tid] = tT[tid]; }

  // precompute xt staging descriptors (cc-invariant): 1296 granules of 16B
  int ldsoff[6], gmoff[6]; bool val[6];
  int cnt = (tid < 16) ? 6 : 5;
  for (int k = 0; k < cnt; ++k){
    int e = tid + (k << 8);
    int rr = e / 72; int rem = e - rr*72; int qq = rem >> 2; int gq4 = rem & 3;
    int gr = p0 - 1 + rr, gq = q0 - 1 + qq;
    val[k]    = ((unsigned)gr < 256u) && ((unsigned)gq < 256u);
    ldsoff[k] = (rr*18+qq)*XT_STRIDE + gq4*8;
    gmoff[k]  = (gr*256+gq)*32 + gq4*8;
  }

  f32x16 acc[2];
  #pragma unroll
  for (int i = 0; i < 16; ++i){ acc[0][i] = 0.f; acc[1][i] = 0.f; }

  int n  = lane & 31;
  int kq = lane >> 5;

  for (int cc = 0; cc < 2; ++cc){
    if (cc) __syncthreads();
    const unsigned short* xb = xup + (((size_t)(b*2+cc)) << 21);
    for (int k = 0; k < cnt; ++k){
      short8 v = {0,0,0,0,0,0,0,0};
      if (val[k]) v = *(const short8*)&xb[gmoff[k]];
      *(short8*)&xt[ldsoff[k]] = v;
    }
    const unsigned short* wbg = aggb + ((size_t)(b*2+cc))*9216;
    for (int e = tid; e < 1152; e += 256){
      *(short8*)&wt[(e >> 2)*XT_STRIDE + (e & 3)*8] = *(const short8*)&wbg[e*8];
    }
    __syncthreads();

    #pragma unroll
    for (int s = 0; s < 9; ++s){
      const int ky = s / 3, kx = s % 3;
      #pragma unroll
      for (int k2 = 0; k2 < 2; ++k2){
        short8 av = *(const short8*)&wt[(s*32 + n)*XT_STRIDE + k2*16 + kq*8];
        #pragma unroll
        for (int tt = 0; tt < 2; ++tt){
          int lr = 2*(2*wv + tt) + (n >> 4);
          int rr = lr + ky;
          int qq = (n & 15) + kx;
          short8 bv = *(const short8*)&xt[(rr*18+qq)*XT_STRIDE + k2*16 + kq*8];
          acc[tt] = __builtin_amdgcn_mfma_f32_32x32x16_bf16(av, bv, acc[tt], 0, 0, 0);
        }
      }
    }
  }

  // epilogue: scale/bias + GELU(exact erf), fp32 stores
  #pragma unroll
  for (int tt = 0; tt < 2; ++tt){
    int lr = 2*(2*wv + tt) + (n >> 4);
    int p = p0 + lr, q = q0 + (n & 15);
    #pragma unroll
    for (int r = 0; r < 16; ++r){
      int o = (r & 3) + 8*(r >> 2) + 4*kq;
      float valv = acc[tt][r]*sSs[o] + tTs[o];
      float gl  = 0.5f*valv*(1.f + erff(valv*0.70710678118f));
      out[(((size_t)(b*32+o)) << 16) + (p << 8) + q] = gl;
    }
  }
}

extern "C" void kernel_launch(void* const* d_in, const int* in_sizes, int n_in,
                              void* d_out, int out_size, void* d_ws, size_t ws_size,
                              hipStream_t stream)
{
  const float* x     = (const float*)d_in[0];
  const float* fc_w  = (const float*)d_in[1];
  const float* bga   = (const float*)d_in[2];
  const float* bba   = (const float*)d_in[3];
  const float* bma   = (const float*)d_in[4];
  const float* bva   = (const float*)d_in[5];
  const float* ch_w  = (const float*)d_in[6];
  const float* ch_b  = (const float*)d_in[7];
  const float* fil_w = (const float*)d_in[8];
  const float* fil_b = (const float*)d_in[9];
  const float* sp_w  = (const float*)d_in[10];
  const float* sp_b  = (const float*)d_in[11];
  const float* k_w   = (const float*)d_in[12];
  const float* k_b   = (const float*)d_in[13];
  const float* weight= (const float*)d_in[14];
  const float* bn_g  = (const float*)d_in[15];
  const float* bn_b  = (const float*)d_in[16];
  const float* bn_m  = (const float*)d_in[17];
  const float* bn_v  = (const float*)d_in[18];

  char* ws = (char*)d_ws;
  float* g   = (float*)(ws + WS_G);
  float* sS  = (float*)(ws + WS_S);
  float* tT  = (float*)(ws + WS_T);
  unsigned short* aggb = (unsigned short*)(ws + WS_AGGB);
  unsigned short* xup  = (unsigned short*)(ws + WS_XUP);
  float* out = (float*)d_out;

  hipLaunchKernelGGL(k_gap,  dim3(512),  dim3(256), 0, stream, x, g);
  hipLaunchKernelGGL(k_aggw, dim3(576),  dim3(256), 0, stream, g, fc_w, bga, bba, bma, bva,
                     ch_w, ch_b, fil_w, fil_b, sp_w, sp_b, k_w, k_b,
                     bn_g, bn_b, bn_m, bn_v, weight, aggb, sS, tT);
  hipLaunchKernelGGL(k_up,   dim3(1024), dim3(256), 0, stream, x, (unsigned int*)xup);
  hipLaunchKernelGGL(k_conv, dim3(2048), dim3(256), 0, stream, xup, aggb, sS, tT, out);
}